// Round 15
// baseline (139.641 us; speedup 1.0000x reference)
//
#include <hip/hip_runtime.h>
#include <hip/hip_fp16.h>
#include <hip/hip_cooperative_groups.h>
#include <stdint.h>

namespace cg = cooperative_groups;

// ---------------------------------------------------------------------------
// NATTEN cross attention, MI355X round 15.
// Window identity: key/value tap for query (x,y) =
//   (clip(x/2-3,0,41)+th, clip(y/2-3,0,41)+tw) in the native 48x48 grid.
// v15: launch-count attack. r13 probe + r14 regression pin ~9us/launch fixed
//   overhead as the dominant cost (kernel work only ~17us total).
//   Launch 1: cooperative (720 x 256thr): phase A = r11 prep verbatim
//   (q/k/v transpose+cvt, w cvt once), grid.sync(), phase B = r11 proj_mfma
//   verbatim. Co-residency: LDS 33.3KB + launch_bounds(256,4) -> 4 blk/CU
//   = 1024 >= 720, so grid.sync cannot deadlock.
//   Launch 2: r13 attn verbatim (MFMA logits, coalesced stores).
// ---------------------------------------------------------------------------

#define C_IN   256
#define C_V    128
#define HQ     96
#define WQ     96
#define HK     48
#define WK     48
#define NPOS_Q (HQ*WQ)    // 9216
#define NPOS_K (HK*WK)    // 2304
#define NH     8
#define DH     32
#define KS     7
#define K2     49

// async global->LDS DMA, 16 B/lane, lane l lands at lds_base + 16*l
#define GLD(gp, lp) __builtin_amdgcn_global_load_lds(                      \
    (const __attribute__((address_space(1))) void*)(uintptr_t)(gp),        \
    (__attribute__((address_space(3))) void*)(uintptr_t)(lp), 16, 0, 0)

typedef _Float16 f16x8 __attribute__((ext_vector_type(8)));
typedef float f32x4 __attribute__((ext_vector_type(4)));

static __device__ __forceinline__ uint32_t pkrtz(float a, float b) {
#if __has_builtin(__builtin_amdgcn_cvt_pkrtz)
  return __builtin_bit_cast(uint32_t, __builtin_amdgcn_cvt_pkrtz(a, b));
#else
  __half2 hv = __floats2half2_rn(a, b);
  return *reinterpret_cast<uint32_t*>(&hv);
#endif
}

// ---- cooperative prep + proj -----------------------------------------------
// grid 720 x 256 thr.
// Phase A (prep, r11 logic):
//   bid 0..287  : q -> xtq[pos][c] f16 (144 pos-tiles x 2 c-halves)
//   bid 288..359: k -> xtk
//   bid 360..395: v -> vt
//   bid 396..411: w_q, w_k -> f16 (grid-stride)
//   bid >= 412  : idle
// grid.sync()
// Phase B (proj, r11 logic): mb = bid%180 (mb<144 Q else K), n0 = (bid/180)*64.
__global__ __launch_bounds__(256, 4) void coop_prep_proj(
    const float* __restrict__ q, const float* __restrict__ k,
    const float* __restrict__ v, const float* __restrict__ wq,
    const float* __restrict__ wk, const float* __restrict__ bq,
    const float* __restrict__ bk, uint32_t* __restrict__ xtq,
    uint32_t* __restrict__ xtk, uint32_t* __restrict__ vt,
    uint32_t* __restrict__ wqh, uint32_t* __restrict__ wkh,
    __half* __restrict__ qo, __half* __restrict__ ko) {
  __shared__ float tile[128 * 65];
  const int bid = blockIdx.x;
  const int u = threadIdx.x;

  // ---------------- phase A: prep ----------------
  if (bid < 360) {                     // q or k transpose+cvt
    const float* src; uint32_t* dst; int npos, tb;
    if (bid < 288) { src = q; dst = xtq; npos = NPOS_Q; tb = bid; }
    else           { src = k; dst = xtk; npos = NPOS_K; tb = bid - 288; }
    const int p0 = (tb >> 1) * 64;
    const int c0 = (tb & 1) * 128;
    for (int i = u; i < 128 * 64; i += 256) {
      int c = i >> 6, p = i & 63;
      tile[c * 65 + p] = src[(size_t)(c0 + c) * npos + p0 + p];
    }
    __syncthreads();
    for (int i = u; i < 64 * 64; i += 256) {
      int p = i >> 6, c2 = i & 63;
      dst[(size_t)(p0 + p) * 128 + (c0 >> 1) + c2] =
          pkrtz(tile[(2 * c2) * 65 + p], tile[(2 * c2 + 1) * 65 + p]);
    }
  } else if (bid < 396) {              // v transpose+cvt
    const int p0 = (bid - 360) * 64;
    for (int i = u; i < 128 * 64; i += 256) {
      int c = i >> 6, p = i & 63;
      tile[c * 65 + p] = v[(size_t)c * NPOS_K + p0 + p];
    }
    __syncthreads();
    for (int i = u; i < 64 * 64; i += 256) {
      int p = i >> 6, c2 = i & 63;
      vt[(size_t)(p0 + p) * 64 + c2] =
          pkrtz(tile[(2 * c2) * 65 + p], tile[(2 * c2 + 1) * 65 + p]);
    }
  } else if (bid < 412) {              // w cvt (no transpose)
    const int tid = (bid - 396) * 256 + u;
    const float2* q2 = (const float2*)wq;
    const float2* k2 = (const float2*)wk;
    for (int j = tid; j < 32768; j += 4096) {
      const float2 a = q2[j];
      wqh[j] = pkrtz(a.x, a.y);
      const float2 b2 = k2[j];
      wkh[j] = pkrtz(b2.x, b2.y);
    }
  }

  cg::this_grid().sync();

  // ---------------- phase B: proj MFMA (r11) ----------------
  const int mb = bid % 180;
  const __half* xt; const __half* wh; const float* bias; __half* outp;
  int m0;
  if (mb < 144) { xt = (const __half*)xtq; wh = (const __half*)wqh; bias = bq;
                  outp = qo; m0 = mb * 64; }
  else          { xt = (const __half*)xtk; wh = (const __half*)wkh; bias = bk;
                  outp = ko; m0 = (mb - 144) * 64; }
  const int n0 = (bid / 180) * 64;

  const int l  = u & 63;
  const int wv = u >> 6;
  const int lr = l & 15;
  const int lk = l >> 4;

  f32x4 acc[4];
#pragma unroll
  for (int nt = 0; nt < 4; ++nt) acc[nt] = (f32x4){0.f, 0.f, 0.f, 0.f};

  const __half* aptr = xt + (size_t)(m0 + wv * 16 + lr) * C_IN + lk * 8;
#pragma unroll
  for (int ks = 0; ks < 8; ++ks) {
    const f16x8 a = *(const f16x8*)(aptr + ks * 32);
#pragma unroll
    for (int nt = 0; nt < 4; ++nt) {
      const f16x8 b = *(const f16x8*)(wh + (size_t)(n0 + nt * 16 + lr) * C_IN +
                                      ks * 32 + lk * 8);
      acc[nt] = __builtin_amdgcn_mfma_f32_16x16x32_f16(a, b, acc[nt], 0, 0, 0);
    }
  }

#pragma unroll
  for (int nt = 0; nt < 4; ++nt) {
    const int o = n0 + nt * 16 + lr;
    const float bv = bias[o];
#pragma unroll
    for (int r = 0; r < 4; ++r) {
      const int pos = m0 + wv * 16 + lk * 4 + r;
      outp[(size_t)pos * C_IN + o] = __float2half(acc[nt][r] + bv);
    }
  }
}

// ---- fused neighborhood attention (r13 verbatim) ---------------------------
__global__ __launch_bounds__(512, 6) void natten_attn(
    const __half* __restrict__ qt, const __half* __restrict__ kt,
    const __half* __restrict__ vt, float* __restrict__ out) {
  __shared__ uint32_t k_s[7168];            // 28672 B
  __shared__ uint32_t v_s[3584];            // 14336 B
  __shared__ uint32_t p_s[2048];            //  8192 B  [h][rt][q] f16; later out_s
  __shared__ float pm_s[8][64];             //  2048 B

  float* out_s = (float*)p_s;               // [8 q][128 c] f32 (aliases p_s)

  const int u  = threadIdx.x;
  const int a  = blockIdx.x;               // 0..47 : x-pair 2a..2a+1
  const int b  = blockIdx.y;               // 0..23 : y-quad 4b..4b+3
  const int sh  = min(max(a - 3, 0), HK - KS);
  const int sw0 = min(max(2 * b - 3, 0), WK - KS);
  const int sw1 = min(max(2 * b - 2, 0), WK - KS);
  const int dlt = sw1 - sw0;               // 0 or 1

  const int l = u & 63;
  const int w = __builtin_amdgcn_readfirstlane(u >> 6);  // wave = head h
  const int lr = l & 15;
  const int lk = l >> 4;

  // ---- k DMA: 28 instrs; LDS 16B-slot s of tap t holds chunk s^((t&1)<<2) --
  for (int idx = w; idx < 28; idx += 8) {
    const int tap = 2 * idx + (l >> 5);
    const int s = l & 31;
    const int g = s ^ ((tap & 1) << 2);
    const int col = min(sw0 + (tap & 7), WK - 1);
    GLD(kt + (size_t)((sh + (tap >> 3)) * WK + col) * C_IN + g * 8,
        (char*)k_s + idx * 1024);
  }
  // ---- v DMA: 14 instrs; 4 region taps each, linear [tap][128c] ------------
  for (int idx = w; idx < 14; idx += 8) {
    const int tap = idx * 4 + (l >> 4);
    const int col = min(sw0 + (tap & 7), WK - 1);
    GLD(vt + (size_t)((sh + (tap >> 3)) * WK + col) * C_V + (l & 15) * 8,
        (char*)v_s + idx * 1024);
  }

  // ---- A-operand: Q rows (8 queries, rows 8-15 dup), head w ----------------
  const int qrow = lr & 7;
  const int aqx = 2 * a + (qrow >> 2);
  const int aqy = 4 * b + (qrow & 3);
  const f16x8 afrag = *(const f16x8*)(
      qt + (size_t)(aqx * WQ + aqy) * C_IN + w * DH + lk * 8);

  __syncthreads();                         // barrier 1: staging done

  // ---- logits MFMA: 4 tap-tiles --------------------------------------------
  f32x4 acc[4];
#pragma unroll
  for (int nt = 0; nt < 4; ++nt) {
    const int t = min(nt * 16 + lr, 55);
    const int byte = t * 512 + (((w * 4 + lk) ^ ((t & 1) << 2)) * 16);
    const f16x8 bfrag = *(const f16x8*)((const char*)k_s + byte);
    acc[nt] = __builtin_amdgcn_mfma_f32_16x16x32_f16(
        afrag, bfrag, (f32x4){0.f, 0.f, 0.f, 0.f}, 0, 0, 0);
  }

  // ---- mask + scale --------------------------------------------------------
  const float scale = 0.17677669529663687f;  // 32^-0.5
  const int qg = lk & 1;                     // row-group (0: q0-3, 1: q4-7)
  float lv[4][4];
#pragma unroll
  for (int nt = 0; nt < 4; ++nt) {
    const int rt = nt * 16 + lr;
    const int tc = rt & 7;
#pragma unroll
    for (int reg = 0; reg < 4; ++reg) {
      const int qq = qg * 4 + reg;
      const int dl = (qq & 2) ? dlt : 0;
      const bool valid = (rt < 56) && ((unsigned)(tc - dl) < 7u);
      lv[nt][reg] = valid ? acc[nt][reg] * scale : -1e30f;
    }
  }

  // ---- softmax per (q): reduce over 16 tap-lanes x 4 tiles ------------------
  float mx[4], sm[4];
#pragma unroll
  for (int reg = 0; reg < 4; ++reg) {
    float m = fmaxf(fmaxf(lv[0][reg], lv[1][reg]), fmaxf(lv[2][reg], lv[3][reg]));
    m = fmaxf(m, __shfl_xor(m, 1));
    m = fmaxf(m, __shfl_xor(m, 2));
    m = fmaxf(m, __shfl_xor(m, 4));
    m = fmaxf(m, __shfl_xor(m, 8));
    mx[reg] = m;
  }
#pragma unroll
  for (int reg = 0; reg < 4; ++reg) {
    float s = 0.f;
#pragma unroll
    for (int nt = 0; nt < 4; ++nt) {
      lv[nt][reg] = __expf(lv[nt][reg] - mx[reg]);
      s += lv[nt][reg];
    }
    s += __shfl_xor(s, 1);
    s += __shfl_xor(s, 2);
    s += __shfl_xor(s, 4);
    s += __shfl_xor(s, 8);
    sm[reg] = 1.f / (8.f * s);
  }

  // ---- p write (lanes < 32 hold real rows 0-7): f16 [h][rt][q] -------------
  if (l < 32) {
#pragma unroll
    for (int nt = 0; nt < 4; ++nt) {
      const int rt = nt * 16 + lr;
      uint2 pk;
      pk.x = pkrtz(lv[nt][0] * sm[0], lv[nt][1] * sm[1]);
      pk.y = pkrtz(lv[nt][2] * sm[2], lv[nt][3] * sm[3]);
      *(uint2*)((char*)p_s + w * 1024 + rt * 16 + qg * 8) = pk;
    }
  }
  __syncthreads();                         // barrier 2: p complete

  // ---- head-sum -> pm_s[q][rt] (first 256 threads) -------------------------
  if (u < 256) {
    const int qp = u & 3;                  // q pair (2qp, 2qp+1)
    const int rt = u >> 2;
    float s0 = 0.f, s1 = 0.f;
#pragma unroll
    for (int h = 0; h < 8; ++h) {
      const uint32_t d = *(const uint32_t*)((const char*)p_s + h * 1024 +
                                            rt * 16 + qp * 4);
      const float2 f = __half22float2(*(const __half2*)&d);
      s0 += f.x;
      s1 += f.y;
    }
    pm_s[2 * qp + 0][rt] = s0;
    pm_s[2 * qp + 1][rt] = s1;
  }
  __syncthreads();                         // barrier 3: pm ready (p_s dead)

  // ---- PV: wave = query w, lane = 2-channel slot ---------------------------
  float ax = 0.f, ay = 0.f;
#pragma unroll
  for (int t0 = 0; t0 < 56; t0 += 4) {
    const float4 pm4 = *(const float4*)&pm_s[w][t0];
    const uint32_t v0 = v_s[(t0 + 0) * 64 + l];
    const uint32_t v1 = v_s[(t0 + 1) * 64 + l];
    const uint32_t v2 = v_s[(t0 + 2) * 64 + l];
    const uint32_t v3 = v_s[(t0 + 3) * 64 + l];
    const float2 f0 = __half22float2(*(const __half2*)&v0);
    const float2 f1 = __half22float2(*(const __half2*)&v1);
    const float2 f2 = __half22float2(*(const __half2*)&v2);
    const float2 f3 = __half22float2(*(const __half2*)&v3);
    ax += pm4.x * f0.x + pm4.y * f1.x + pm4.z * f2.x + pm4.w * f3.x;
    ay += pm4.x * f0.y + pm4.y * f1.y + pm4.z * f2.y + pm4.w * f3.y;
  }

  // ---- stage results to LDS, then coalesced float4 stores ------------------
  *(float2*)&out_s[w * 128 + 2 * l] = make_float2(ax, ay);
  __syncthreads();                         // barrier 4: out_s ready
  if (u < 256) {
    const int c = u & 127;
    const int qxl = u >> 7;                // 0..1
    float4 o;
    o.x = out_s[(qxl * 4 + 0) * 128 + c];
    o.y = out_s[(qxl * 4 + 1) * 128 + c];
    o.z = out_s[(qxl * 4 + 2) * 128 + c];
    o.w = out_s[(qxl * 4 + 3) * 128 + c];
    *(float4*)&out[(size_t)c * NPOS_Q + (2 * a + qxl) * WQ + 4 * b] = o;
  }
}

// ---------------------------------------------------------------------------
extern "C" void kernel_launch(void* const* d_in, const int* in_sizes, int n_in,
                              void* d_out, int out_size, void* d_ws, size_t ws_size,
                              hipStream_t stream) {
  const float* q   = (const float*)d_in[0];
  const float* k   = (const float*)d_in[1];
  const float* v   = (const float*)d_in[2];
  const float* w_q = (const float*)d_in[3];
  const float* b_q = (const float*)d_in[4];
  const float* w_k = (const float*)d_in[5];
  const float* b_k = (const float*)d_in[6];
  float* out = (float*)d_out;

  uint32_t* xtq = (uint32_t*)d_ws;                 // [9216][128] u32 (f16 x^T)
  uint32_t* xtk = xtq + (size_t)NPOS_Q * 128;      // [2304][128]
  uint32_t* vt  = xtk + (size_t)NPOS_K * 128;      // [2304][64]
  uint32_t* wqh = vt + (size_t)NPOS_K * 64;        // [256][128]
  uint32_t* wkh = wqh + 32768;                     // [256][128]
  __half* qt = (__half*)(wkh + 32768);             // [9216][256] f16
  __half* kt = qt + (size_t)NPOS_Q * C_IN;         // [2304][256]

  void* args[] = {&q, &k, &v, &w_q, &w_k, &b_q, &b_k,
                  &xtq, &xtk, &vt, &wqh, &wkh, &qt, &kt};
  hipLaunchCooperativeKernel((const void*)coop_prep_proj, dim3(720), dim3(256),
                             args, 0, stream);
  natten_attn<<<dim3(HQ / 2, WQ / 4), 512, 0, stream>>>(
      qt, kt, (const __half*)vt, out);
}

// Round 16
// 50.494 us; speedup vs baseline: 2.7655x; 2.7655x over previous
//
#include <hip/hip_runtime.h>
#include <hip/hip_fp16.h>
#include <stdint.h>

// ---------------------------------------------------------------------------
// NATTEN cross attention, MI355X round 16.
// Window identity: key/value tap for query (x,y) =
//   (clip(x/2-3,0,41)+th, clip(y/2-3,0,41)+tw) in the native 48x48 grid.
// v16: 2 launches, no grid.sync (r15's coop grid.sync cost ~90us -> revert).
//   proj_fused3 = r14's verified per-block x-transpose + w STAGED TO LDS ONCE
//   per block outside the MFMA loop (r14's mistake: per-fragment cvt in the
//   hot loop, 144x redundant). Two 128c K-chunks, odd-pitch (68 u32) wh ->
//   staging writes and B-frag reads both bank-clean. LDS: xa 16.9KB +
//   (ts|wh overlapped) 34.8KB = 51.7KB -> 3 blocks/CU.
//   natten_attn = r13 verbatim.
// ---------------------------------------------------------------------------

#define C_IN   256
#define C_V    128
#define HQ     96
#define WQ     96
#define HK     48
#define WK     48
#define NPOS_Q (HQ*WQ)    // 9216
#define NPOS_K (HK*WK)    // 2304
#define NH     8
#define DH     32
#define KS     7
#define K2     49

// async global->LDS DMA, 16 B/lane, lane l lands at lds_base + 16*l
#define GLD(gp, lp) __builtin_amdgcn_global_load_lds(                      \
    (const __attribute__((address_space(1))) void*)(uintptr_t)(gp),        \
    (__attribute__((address_space(3))) void*)(uintptr_t)(lp), 16, 0, 0)

typedef _Float16 f16x8 __attribute__((ext_vector_type(8)));
typedef float f32x4 __attribute__((ext_vector_type(4)));

static __device__ __forceinline__ uint32_t pkrtz(float a, float b) {
#if __has_builtin(__builtin_amdgcn_cvt_pkrtz)
  return __builtin_bit_cast(uint32_t, __builtin_amdgcn_cvt_pkrtz(a, b));
#else
  __half2 hv = __floats2half2_rn(a, b);
  return *reinterpret_cast<uint32_t*>(&hv);
#endif
}

// ---- fused projection + v transpose ----------------------------------------
// grid (396, 2), 256 thr.
//   mb < 288          : Q proj, pos tile m0 = mb*32
//   288 <= mb < 360   : K proj, pos tile (mb-288)*32
//   mb >= 360 (y==0)  : v transpose+cvt tail (36 blocks)
// Layout: xa = smem[0..4223] (u32 view, 32 pos x 132); region2 = smem+4224:
//   phase T: ts [64 c][33] f32; phase W: wh [128 o][68] u32 (f16 pairs).
__global__ __launch_bounds__(256) void proj_fused3(
    const float* __restrict__ q, const float* __restrict__ k,
    const float* __restrict__ v, const float* __restrict__ wq,
    const float* __restrict__ wk, const float* __restrict__ bq,
    const float* __restrict__ bk, __half* __restrict__ qo,
    __half* __restrict__ ko, uint32_t* __restrict__ vt) {
  __shared__ uint32_t smem[12928];           // 51712 B

  const int mb = blockIdx.x;
  const int u  = threadIdx.x;

  if (mb >= 360) {                           // ---- v transpose tail ----
    if (blockIdx.y) return;
    float* tile = (float*)smem;              // [128][65] fits (33.3KB)
    const int p0 = (mb - 360) * 64;
    for (int i = u; i < 128 * 64; i += 256) {
      int c = i >> 6, p = i & 63;
      tile[c * 65 + p] = v[(size_t)c * NPOS_K + p0 + p];
    }
    __syncthreads();
    for (int i = u; i < 64 * 64; i += 256) {
      int p = i >> 6, c2 = i & 63;
      vt[(size_t)(p0 + p) * 64 + c2] =
          pkrtz(tile[(2 * c2) * 65 + p], tile[(2 * c2 + 1) * 65 + p]);
    }
    return;
  }

  uint32_t* xa = smem;                       // [32 pos][132] f16-pair
  float*    ts = (float*)(smem + 4224);      // [64 c][33] f32
  uint32_t* wh = smem + 4224;                // [128 o][68] f16-pair

  const float* x; const float* w; const float* bias; __half* outp;
  int npos, m0;
  if (mb < 288) { x = q; w = wq; bias = bq; outp = qo; npos = NPOS_Q; m0 = mb * 32; }
  else          { x = k; w = wk; bias = bk; outp = ko; npos = NPOS_K; m0 = (mb - 288) * 32; }
  const int obase = blockIdx.y * 128;

  // ---- phase T: stage + transpose + f16-pack x tile (4 chunks of 64 c) -----
  for (int cc = 0; cc < 4; ++cc) {
    for (int i = u; i < 64 * 32; i += 256) {
      int cr = i >> 5, p = i & 31;
      ts[cr * 33 + p] = x[(size_t)(cc * 64 + cr) * npos + m0 + p];
    }
    __syncthreads();
    for (int i = u; i < 32 * 32; i += 256) {
      int p = i >> 5, c2 = i & 31;
      xa[p * 132 + cc * 32 + c2] =
          pkrtz(ts[(2 * c2) * 33 + p], ts[(2 * c2 + 1) * 33 + p]);
    }
    __syncthreads();
  }

  // ---- MFMA with LDS-staged w: 2 K-chunks of 128 c -------------------------
  const int l  = u & 63;
  const int wv = u >> 6;
  const int lr = l & 15;
  const int lk = l >> 4;
  const int pg = wv >> 1;                    // pos group (16 rows)
  const int og = wv & 1;                     // o group (64 cols)
  const int arow = pg * 16 + lr;

  f32x4 acc[4];
#pragma unroll
  for (int nt = 0; nt < 4; ++nt) acc[nt] = (f32x4){0.f, 0.f, 0.f, 0.f};

  for (int kc = 0; kc < 2; ++kc) {
    // stage wh[o_local][c2l] (128 o x 64 u32), odd pitch 68; coalesced float2
    for (int i = u; i < 128 * 64; i += 256) {
      const int ol = i >> 6, c2l = i & 63;
      const float2 wv2 = *(const float2*)&w[(size_t)(obase + ol) * C_IN +
                                            kc * 128 + 2 * c2l];
      wh[ol * 68 + c2l] = pkrtz(wv2.x, wv2.y);
    }
    __syncthreads();
#pragma unroll
    for (int ks2 = 0; ks2 < 4; ++ks2) {
      const int ks = kc * 4 + ks2;
      const f16x8 a = *(const f16x8*)((const char*)xa + arow * 528 + ks * 64 + lk * 16);
#pragma unroll
      for (int nt = 0; nt < 4; ++nt) {
        const int ol = og * 64 + nt * 16 + lr;
        const f16x8 b = *(const f16x8*)((const char*)wh + ol * 272 + ks2 * 64 + lk * 16);
        acc[nt] = __builtin_amdgcn_mfma_f32_16x16x32_f16(a, b, acc[nt], 0, 0, 0);
      }
    }
    __syncthreads();                         // reads done before restage
  }

  // ---- epilogue: bias + f16 store ------------------------------------------
#pragma unroll
  for (int nt = 0; nt < 4; ++nt) {
    const int o = obase + og * 64 + nt * 16 + lr;
    const float bv = bias[o];
#pragma unroll
    for (int r = 0; r < 4; ++r) {
      const int pos = m0 + pg * 16 + lk * 4 + r;
      outp[(size_t)pos * C_IN + o] = __float2half(acc[nt][r] + bv);
    }
  }
}

// ---- fused neighborhood attention (r13 verbatim) ---------------------------
__global__ __launch_bounds__(512, 6) void natten_attn(
    const __half* __restrict__ qt, const __half* __restrict__ kt,
    const __half* __restrict__ vt, float* __restrict__ out) {
  __shared__ uint32_t k_s[7168];            // 28672 B
  __shared__ uint32_t v_s[3584];            // 14336 B
  __shared__ uint32_t p_s[2048];            //  8192 B  [h][rt][q] f16; later out_s
  __shared__ float pm_s[8][64];             //  2048 B

  float* out_s = (float*)p_s;               // [8 q][128 c] f32 (aliases p_s)

  const int u  = threadIdx.x;
  const int a  = blockIdx.x;               // 0..47 : x-pair 2a..2a+1
  const int b  = blockIdx.y;               // 0..23 : y-quad 4b..4b+3
  const int sh  = min(max(a - 3, 0), HK - KS);
  const int sw0 = min(max(2 * b - 3, 0), WK - KS);
  const int sw1 = min(max(2 * b - 2, 0), WK - KS);
  const int dlt = sw1 - sw0;               // 0 or 1

  const int l = u & 63;
  const int w = __builtin_amdgcn_readfirstlane(u >> 6);  // wave = head h
  const int lr = l & 15;
  const int lk = l >> 4;

  // ---- k DMA: 28 instrs; LDS 16B-slot s of tap t holds chunk s^((t&1)<<2) --
  for (int idx = w; idx < 28; idx += 8) {
    const int tap = 2 * idx + (l >> 5);
    const int s = l & 31;
    const int g = s ^ ((tap & 1) << 2);
    const int col = min(sw0 + (tap & 7), WK - 1);
    GLD(kt + (size_t)((sh + (tap >> 3)) * WK + col) * C_IN + g * 8,
        (char*)k_s + idx * 1024);
  }
  // ---- v DMA: 14 instrs; 4 region taps each, linear [tap][128c] ------------
  for (int idx = w; idx < 14; idx += 8) {
    const int tap = idx * 4 + (l >> 4);
    const int col = min(sw0 + (tap & 7), WK - 1);
    GLD(vt + (size_t)((sh + (tap >> 3)) * WK + col) * C_V + (l & 15) * 8,
        (char*)v_s + idx * 1024);
  }

  // ---- A-operand: Q rows (8 queries, rows 8-15 dup), head w ----------------
  const int qrow = lr & 7;
  const int aqx = 2 * a + (qrow >> 2);
  const int aqy = 4 * b + (qrow & 3);
  const f16x8 afrag = *(const f16x8*)(
      qt + (size_t)(aqx * WQ + aqy) * C_IN + w * DH + lk * 8);

  __syncthreads();                         // barrier 1: staging done

  // ---- logits MFMA: 4 tap-tiles --------------------------------------------
  f32x4 acc[4];
#pragma unroll
  for (int nt = 0; nt < 4; ++nt) {
    const int t = min(nt * 16 + lr, 55);
    const int byte = t * 512 + (((w * 4 + lk) ^ ((t & 1) << 2)) * 16);
    const f16x8 bfrag = *(const f16x8*)((const char*)k_s + byte);
    acc[nt] = __builtin_amdgcn_mfma_f32_16x16x32_f16(
        afrag, bfrag, (f32x4){0.f, 0.f, 0.f, 0.f}, 0, 0, 0);
  }

  // ---- mask + scale --------------------------------------------------------
  const float scale = 0.17677669529663687f;  // 32^-0.5
  const int qg = lk & 1;                     // row-group (0: q0-3, 1: q4-7)
  float lv[4][4];
#pragma unroll
  for (int nt = 0; nt < 4; ++nt) {
    const int rt = nt * 16 + lr;
    const int tc = rt & 7;
#pragma unroll
    for (int reg = 0; reg < 4; ++reg) {
      const int qq = qg * 4 + reg;
      const int dl = (qq & 2) ? dlt : 0;
      const bool valid = (rt < 56) && ((unsigned)(tc - dl) < 7u);
      lv[nt][reg] = valid ? acc[nt][reg] * scale : -1e30f;
    }
  }

  // ---- softmax per (q): reduce over 16 tap-lanes x 4 tiles ------------------
  float mx[4], sm[4];
#pragma unroll
  for (int reg = 0; reg < 4; ++reg) {
    float m = fmaxf(fmaxf(lv[0][reg], lv[1][reg]), fmaxf(lv[2][reg], lv[3][reg]));
    m = fmaxf(m, __shfl_xor(m, 1));
    m = fmaxf(m, __shfl_xor(m, 2));
    m = fmaxf(m, __shfl_xor(m, 4));
    m = fmaxf(m, __shfl_xor(m, 8));
    mx[reg] = m;
  }
#pragma unroll
  for (int reg = 0; reg < 4; ++reg) {
    float s = 0.f;
#pragma unroll
    for (int nt = 0; nt < 4; ++nt) {
      lv[nt][reg] = __expf(lv[nt][reg] - mx[reg]);
      s += lv[nt][reg];
    }
    s += __shfl_xor(s, 1);
    s += __shfl_xor(s, 2);
    s += __shfl_xor(s, 4);
    s += __shfl_xor(s, 8);
    sm[reg] = 1.f / (8.f * s);
  }

  // ---- p write (lanes < 32 hold real rows 0-7): f16 [h][rt][q] -------------
  if (l < 32) {
#pragma unroll
    for (int nt = 0; nt < 4; ++nt) {
      const int rt = nt * 16 + lr;
      uint2 pk;
      pk.x = pkrtz(lv[nt][0] * sm[0], lv[nt][1] * sm[1]);
      pk.y = pkrtz(lv[nt][2] * sm[2], lv[nt][3] * sm[3]);
      *(uint2*)((char*)p_s + w * 1024 + rt * 16 + qg * 8) = pk;
    }
  }
  __syncthreads();                         // barrier 2: p complete

  // ---- head-sum -> pm_s[q][rt] (first 256 threads) -------------------------
  if (u < 256) {
    const int qp = u & 3;                  // q pair (2qp, 2qp+1)
    const int rt = u >> 2;
    float s0 = 0.f, s1 = 0.f;
#pragma unroll
    for (int h = 0; h < 8; ++h) {
      const uint32_t d = *(const uint32_t*)((const char*)p_s + h * 1024 +
                                            rt * 16 + qp * 4);
      const float2 f = __half22float2(*(const __half2*)&d);
      s0 += f.x;
      s1 += f.y;
    }
    pm_s[2 * qp + 0][rt] = s0;
    pm_s[2 * qp + 1][rt] = s1;
  }
  __syncthreads();                         // barrier 3: pm ready (p_s dead)

  // ---- PV: wave = query w, lane = 2-channel slot ---------------------------
  float ax = 0.f, ay = 0.f;
#pragma unroll
  for (int t0 = 0; t0 < 56; t0 += 4) {
    const float4 pm4 = *(const float4*)&pm_s[w][t0];
    const uint32_t v0 = v_s[(t0 + 0) * 64 + l];
    const uint32_t v1 = v_s[(t0 + 1) * 64 + l];
    const uint32_t v2 = v_s[(t0 + 2) * 64 + l];
    const uint32_t v3 = v_s[(t0 + 3) * 64 + l];
    const float2 f0 = __half22float2(*(const __half2*)&v0);
    const float2 f1 = __half22float2(*(const __half2*)&v1);
    const float2 f2 = __half22float2(*(const __half2*)&v2);
    const float2 f3 = __half22float2(*(const __half2*)&v3);
    ax += pm4.x * f0.x + pm4.y * f1.x + pm4.z * f2.x + pm4.w * f3.x;
    ay += pm4.x * f0.y + pm4.y * f1.y + pm4.z * f2.y + pm4.w * f3.y;
  }

  // ---- stage results to LDS, then coalesced float4 stores ------------------
  *(float2*)&out_s[w * 128 + 2 * l] = make_float2(ax, ay);
  __syncthreads();                         // barrier 4: out_s ready
  if (u < 256) {
    const int c = u & 127;
    const int qxl = u >> 7;                // 0..1
    float4 o;
    o.x = out_s[(qxl * 4 + 0) * 128 + c];
    o.y = out_s[(qxl * 4 + 1) * 128 + c];
    o.z = out_s[(qxl * 4 + 2) * 128 + c];
    o.w = out_s[(qxl * 4 + 3) * 128 + c];
    *(float4*)&out[(size_t)c * NPOS_Q + (2 * a + qxl) * WQ + 4 * b] = o;
  }
}

// ---------------------------------------------------------------------------
extern "C" void kernel_launch(void* const* d_in, const int* in_sizes, int n_in,
                              void* d_out, int out_size, void* d_ws, size_t ws_size,
                              hipStream_t stream) {
  const float* q   = (const float*)d_in[0];
  const float* k   = (const float*)d_in[1];
  const float* v   = (const float*)d_in[2];
  const float* w_q = (const float*)d_in[3];
  const float* b_q = (const float*)d_in[4];
  const float* w_k = (const float*)d_in[5];
  const float* b_k = (const float*)d_in[6];
  float* out = (float*)d_out;

  __half* vt = (__half*)d_ws;                      // [2304][128] f16
  __half* qt = vt + (size_t)NPOS_K * C_V;          // [9216][256] f16
  __half* kt = qt + (size_t)NPOS_Q * C_IN;         // [2304][256] f16

  proj_fused3<<<dim3(396, 2), 256, 0, stream>>>(q, k, v, w_q, w_k, b_q, b_k,
                                                qt, kt, (uint32_t*)vt);
  natten_attn<<<dim3(HQ / 2, WQ / 4), 512, 0, stream>>>(qt, kt, vt, out);
}

// Round 17
// 33.192 us; speedup vs baseline: 4.2071x; 1.5213x over previous
//
#include <hip/hip_runtime.h>
#include <hip/hip_fp16.h>
#include <stdint.h>

// ---------------------------------------------------------------------------
// NATTEN cross attention, MI355X round 17.
// Window identity: key/value tap for query (x,y) =
//   (clip(x/2-3,0,41)+th, clip(y/2-3,0,41)+tw) in the native 48x48 grid.
// v17: r16 rocprof showed proj variants are latency-bound on 16B-scattered
//   fragment loads (VALUBusy 7.9%, MfmaUtil 1.1%, occ 27%). Fix: prep emits
//   xt and w in MFMA-FRAGMENT ORDER - uint4 slot (tile, ks, lane) holds the
//   exact 16B lane needs (A: m=l&15, kchunk=l>>4 - r11 HW-verified; B:
//   w[o][c] c-contig, no transpose). proj = zero-LDS zero-barrier stream of
//   1KB-coalesced loads + MFMA. prep vectorized (float4 reads, uint4 stores).
//   attn = r13 verbatim. 3 launches.
// ---------------------------------------------------------------------------

#define C_IN   256
#define C_V    128
#define HQ     96
#define WQ     96
#define HK     48
#define WK     48
#define NPOS_Q (HQ*WQ)    // 9216
#define NPOS_K (HK*WK)    // 2304
#define NH     8
#define DH     32
#define KS     7
#define K2     49

// async global->LDS DMA, 16 B/lane, lane l lands at lds_base + 16*l
#define GLD(gp, lp) __builtin_amdgcn_global_load_lds(                      \
    (const __attribute__((address_space(1))) void*)(uintptr_t)(gp),        \
    (__attribute__((address_space(3))) void*)(uintptr_t)(lp), 16, 0, 0)

typedef _Float16 f16x8 __attribute__((ext_vector_type(8)));
typedef float f32x4 __attribute__((ext_vector_type(4)));

static __device__ __forceinline__ uint32_t pkrtz(float a, float b) {
#if __has_builtin(__builtin_amdgcn_cvt_pkrtz)
  return __builtin_bit_cast(uint32_t, __builtin_amdgcn_cvt_pkrtz(a, b));
#else
  __half2 hv = __floats2half2_rn(a, b);
  return *reinterpret_cast<uint32_t*>(&hv);
#endif
}

// ---- prep: frag-layout xt/w + linear vt ------------------------------------
// grid 220 x 256 thr.
//   bid 0..143  : Q 64-pos transpose -> xtqf frag slots (tile, ks, lane)
//   bid 144..179: K same -> xtkf
//   bid 180..215: v transpose+cvt -> vt[pos][c2] u32 (attn layout)
//   bid 216..219: w -> frag slots (no transpose; B wants c-contig)
__global__ __launch_bounds__(256) void prep(
    const float* __restrict__ q, const float* __restrict__ k,
    const float* __restrict__ v, const float* __restrict__ wq,
    const float* __restrict__ wk, uint4* __restrict__ xtqf,
    uint4* __restrict__ xtkf, uint32_t* __restrict__ vt,
    uint4* __restrict__ wqf, uint4* __restrict__ wkf) {
  __shared__ float ts[8704];                 // [128 c][68] f32, 34.8 KB
  const int bid = blockIdx.x;
  const int u = threadIdx.x;

  if (bid < 180) {                           // ---- q/k transpose -> frag ----
    const float* x; uint4* dst; int npos, p0;
    if (bid < 144) { x = q; dst = xtqf; npos = NPOS_Q; p0 = bid * 64; }
    else           { x = k; dst = xtkf; npos = NPOS_K; p0 = (bid - 144) * 64; }
    const int t0 = p0 >> 4;                  // 4 pos-tiles per block
    const int l = u & 63, m = l & 15, ch = l >> 4, ksl = u >> 6;
    for (int cc = 0; cc < 2; ++cc) {         // two 128-c chunks
      __syncthreads();
#pragma unroll
      for (int it = 0; it < 8; ++it) {       // stage 128c x 64pos, float4
        const int idx = it * 256 + u;
        const int c = idx >> 4, qd = (idx & 15) * 4;
        *(float4*)&ts[c * 68 + qd] =
            *(const float4*)&x[(size_t)(cc * 128 + c) * npos + p0 + qd];
      }
      __syncthreads();
#pragma unroll
      for (int tl = 0; tl < 4; ++tl) {       // frag pack + coalesced store
        const int cb = ksl * 32 + ch * 8;    // c within chunk
        const int pl = tl * 16 + m;
        uint4 pk4;
        pk4.x = pkrtz(ts[(cb + 0) * 68 + pl], ts[(cb + 1) * 68 + pl]);
        pk4.y = pkrtz(ts[(cb + 2) * 68 + pl], ts[(cb + 3) * 68 + pl]);
        pk4.z = pkrtz(ts[(cb + 4) * 68 + pl], ts[(cb + 5) * 68 + pl]);
        pk4.w = pkrtz(ts[(cb + 6) * 68 + pl], ts[(cb + 7) * 68 + pl]);
        dst[((size_t)(t0 + tl) * 8 + cc * 4 + ksl) * 64 + l] = pk4;
      }
    }
  } else if (bid < 216) {                    // ---- v transpose+cvt ----
    const int p0 = (bid - 180) * 64;
#pragma unroll
    for (int it = 0; it < 8; ++it) {
      const int idx = it * 256 + u;
      const int c = idx >> 4, qd = (idx & 15) * 4;
      *(float4*)&ts[c * 68 + qd] =
          *(const float4*)&v[(size_t)c * NPOS_K + p0 + qd];
    }
    __syncthreads();
#pragma unroll
    for (int it = 0; it < 8; ++it) {
      const int idx = it * 256 + u;
      const int p = idx >> 5, c22 = (idx & 31) * 2;   // c2 pair
      uint2 w2;
      w2.x = pkrtz(ts[(2 * c22 + 0) * 68 + p], ts[(2 * c22 + 1) * 68 + p]);
      w2.y = pkrtz(ts[(2 * c22 + 2) * 68 + p], ts[(2 * c22 + 3) * 68 + p]);
      *(uint2*)&vt[(size_t)(p0 + p) * 64 + c22] = w2;
    }
  } else {                                   // ---- w -> frag (no transpose) -
    const int wb = bid - 216;
    const float* src = (wb < 2) ? wq : wk;
    uint4* dst = (wb < 2) ? wqf : wkf;
    const int half = wb & 1;                 // o-tiles 0-7 or 8-15
#pragma unroll
    for (int it = 0; it < 16; ++it) {
      const int s = it * 256 + u;
      const int otl = half * 8 + (s >> 9);
      const int ks = (s >> 6) & 7;
      const int l = s & 63;
      const int o = otl * 16 + (l & 15);
      const int c0 = ks * 32 + (l >> 4) * 8;
      const float4 a  = *(const float4*)&src[(size_t)o * C_IN + c0];
      const float4 b2 = *(const float4*)&src[(size_t)o * C_IN + c0 + 4];
      uint4 pk4;
      pk4.x = pkrtz(a.x, a.y);
      pk4.y = pkrtz(a.z, a.w);
      pk4.z = pkrtz(b2.x, b2.y);
      pk4.w = pkrtz(b2.z, b2.w);
      dst[((size_t)otl * 8 + ks) * 64 + l] = pk4;
    }
  }
}

// ---- streaming MFMA projection (zero LDS, zero barriers) -------------------
// grid (180, 4); wave = 16-pos tile x 64 o. All loads 1KB lane-consecutive.
__global__ __launch_bounds__(256) void proj_mfma(
    const uint4* __restrict__ xtqf, const uint4* __restrict__ xtkf,
    const uint4* __restrict__ wqf, const uint4* __restrict__ wkf,
    const float* __restrict__ bq, const float* __restrict__ bk,
    __half* __restrict__ qo, __half* __restrict__ ko) {
  const int mb = blockIdx.x;
  const uint4* xf; const uint4* wf; const float* bias; __half* outp;
  int m0;
  if (mb < 144) { xf = xtqf; wf = wqf; bias = bq; outp = qo; m0 = mb * 64; }
  else          { xf = xtkf; wf = wkf; bias = bk; outp = ko; m0 = (mb - 144) * 64; }
  const int n0 = blockIdx.y * 64;

  const int u  = threadIdx.x;
  const int l  = u & 63;
  const int wv = u >> 6;
  const int lr = l & 15;
  const int lk = l >> 4;
  const int tile   = (m0 >> 4) + wv;
  const int otile0 = n0 >> 4;

  f32x4 acc[4];
#pragma unroll
  for (int nt = 0; nt < 4; ++nt) acc[nt] = (f32x4){0.f, 0.f, 0.f, 0.f};

#pragma unroll
  for (int ks = 0; ks < 8; ++ks) {
    const uint4 av = xf[((size_t)tile * 8 + ks) * 64 + l];
    const f16x8 a = __builtin_bit_cast(f16x8, av);
#pragma unroll
    for (int nt = 0; nt < 4; ++nt) {
      const uint4 bv = wf[((size_t)(otile0 + nt) * 8 + ks) * 64 + l];
      acc[nt] = __builtin_amdgcn_mfma_f32_16x16x32_f16(
          a, __builtin_bit_cast(f16x8, bv), acc[nt], 0, 0, 0);
    }
  }

#pragma unroll
  for (int nt = 0; nt < 4; ++nt) {
    const int o = n0 + nt * 16 + lr;
    const float bv = bias[o];
#pragma unroll
    for (int r = 0; r < 4; ++r) {
      const int pos = m0 + wv * 16 + lk * 4 + r;
      outp[(size_t)pos * C_IN + o] = __float2half(acc[nt][r] + bv);
    }
  }
}

// ---- fused neighborhood attention (r13 verbatim) ---------------------------
__global__ __launch_bounds__(512, 6) void natten_attn(
    const __half* __restrict__ qt, const __half* __restrict__ kt,
    const __half* __restrict__ vt, float* __restrict__ out) {
  __shared__ uint32_t k_s[7168];            // 28672 B
  __shared__ uint32_t v_s[3584];            // 14336 B
  __shared__ uint32_t p_s[2048];            //  8192 B  [h][rt][q] f16; later out_s
  __shared__ float pm_s[8][64];             //  2048 B

  float* out_s = (float*)p_s;               // [8 q][128 c] f32 (aliases p_s)

  const int u  = threadIdx.x;
  const int a  = blockIdx.x;               // 0..47 : x-pair 2a..2a+1
  const int b  = blockIdx.y;               // 0..23 : y-quad 4b..4b+3
  const int sh  = min(max(a - 3, 0), HK - KS);
  const int sw0 = min(max(2 * b - 3, 0), WK - KS);
  const int sw1 = min(max(2 * b - 2, 0), WK - KS);
  const int dlt = sw1 - sw0;               // 0 or 1

  const int l = u & 63;
  const int w = __builtin_amdgcn_readfirstlane(u >> 6);  // wave = head h
  const int lr = l & 15;
  const int lk = l >> 4;

  // ---- k DMA: 28 instrs; LDS 16B-slot s of tap t holds chunk s^((t&1)<<2) --
  for (int idx = w; idx < 28; idx += 8) {
    const int tap = 2 * idx + (l >> 5);
    const int s = l & 31;
    const int g = s ^ ((tap & 1) << 2);
    const int col = min(sw0 + (tap & 7), WK - 1);
    GLD(kt + (size_t)((sh + (tap >> 3)) * WK + col) * C_IN + g * 8,
        (char*)k_s + idx * 1024);
  }
  // ---- v DMA: 14 instrs; 4 region taps each, linear [tap][128c] ------------
  for (int idx = w; idx < 14; idx += 8) {
    const int tap = idx * 4 + (l >> 4);
    const int col = min(sw0 + (tap & 7), WK - 1);
    GLD(vt + (size_t)((sh + (tap >> 3)) * WK + col) * C_V + (l & 15) * 8,
        (char*)v_s + idx * 1024);
  }

  // ---- A-operand: Q rows (8 queries, rows 8-15 dup), head w ----------------
  const int qrow = lr & 7;
  const int aqx = 2 * a + (qrow >> 2);
  const int aqy = 4 * b + (qrow & 3);
  const f16x8 afrag = *(const f16x8*)(
      qt + (size_t)(aqx * WQ + aqy) * C_IN + w * DH + lk * 8);

  __syncthreads();                         // barrier 1: staging done

  // ---- logits MFMA: 4 tap-tiles --------------------------------------------
  f32x4 acc[4];
#pragma unroll
  for (int nt = 0; nt < 4; ++nt) {
    const int t = min(nt * 16 + lr, 55);
    const int byte = t * 512 + (((w * 4 + lk) ^ ((t & 1) << 2)) * 16);
    const f16x8 bfrag = *(const f16x8*)((const char*)k_s + byte);
    acc[nt] = __builtin_amdgcn_mfma_f32_16x16x32_f16(
        afrag, bfrag, (f32x4){0.f, 0.f, 0.f, 0.f}, 0, 0, 0);
  }

  // ---- mask + scale --------------------------------------------------------
  const float scale = 0.17677669529663687f;  // 32^-0.5
  const int qg = lk & 1;                     // row-group (0: q0-3, 1: q4-7)
  float lv[4][4];
#pragma unroll
  for (int nt = 0; nt < 4; ++nt) {
    const int rt = nt * 16 + lr;
    const int tc = rt & 7;
#pragma unroll
    for (int reg = 0; reg < 4; ++reg) {
      const int qq = qg * 4 + reg;
      const int dl = (qq & 2) ? dlt : 0;
      const bool valid = (rt < 56) && ((unsigned)(tc - dl) < 7u);
      lv[nt][reg] = valid ? acc[nt][reg] * scale : -1e30f;
    }
  }

  // ---- softmax per (q): reduce over 16 tap-lanes x 4 tiles ------------------
  float mx[4], sm[4];
#pragma unroll
  for (int reg = 0; reg < 4; ++reg) {
    float m = fmaxf(fmaxf(lv[0][reg], lv[1][reg]), fmaxf(lv[2][reg], lv[3][reg]));
    m = fmaxf(m, __shfl_xor(m, 1));
    m = fmaxf(m, __shfl_xor(m, 2));
    m = fmaxf(m, __shfl_xor(m, 4));
    m = fmaxf(m, __shfl_xor(m, 8));
    mx[reg] = m;
  }
#pragma unroll
  for (int reg = 0; reg < 4; ++reg) {
    float s = 0.f;
#pragma unroll
    for (int nt = 0; nt < 4; ++nt) {
      lv[nt][reg] = __expf(lv[nt][reg] - mx[reg]);
      s += lv[nt][reg];
    }
    s += __shfl_xor(s, 1);
    s += __shfl_xor(s, 2);
    s += __shfl_xor(s, 4);
    s += __shfl_xor(s, 8);
    sm[reg] = 1.f / (8.f * s);
  }

  // ---- p write (lanes < 32 hold real rows 0-7): f16 [h][rt][q] -------------
  if (l < 32) {
#pragma unroll
    for (int nt = 0; nt < 4; ++nt) {
      const int rt = nt * 16 + lr;
      uint2 pk;
      pk.x = pkrtz(lv[nt][0] * sm[0], lv[nt][1] * sm[1]);
      pk.y = pkrtz(lv[nt][2] * sm[2], lv[nt][3] * sm[3]);
      *(uint2*)((char*)p_s + w * 1024 + rt * 16 + qg * 8) = pk;
    }
  }
  __syncthreads();                         // barrier 2: p complete

  // ---- head-sum -> pm_s[q][rt] (first 256 threads) -------------------------
  if (u < 256) {
    const int qp = u & 3;                  // q pair (2qp, 2qp+1)
    const int rt = u >> 2;
    float s0 = 0.f, s1 = 0.f;
#pragma unroll
    for (int h = 0; h < 8; ++h) {
      const uint32_t d = *(const uint32_t*)((const char*)p_s + h * 1024 +
                                            rt * 16 + qp * 4);
      const float2 f = __half22float2(*(const __half2*)&d);
      s0 += f.x;
      s1 += f.y;
    }
    pm_s[2 * qp + 0][rt] = s0;
    pm_s[2 * qp + 1][rt] = s1;
  }
  __syncthreads();                         // barrier 3: pm ready (p_s dead)

  // ---- PV: wave = query w, lane = 2-channel slot ---------------------------
  float ax = 0.f, ay = 0.f;
#pragma unroll
  for (int t0 = 0; t0 < 56; t0 += 4) {
    const float4 pm4 = *(const float4*)&pm_s[w][t0];
    const uint32_t v0 = v_s[(t0 + 0) * 64 + l];
    const uint32_t v1 = v_s[(t0 + 1) * 64 + l];
    const uint32_t v2 = v_s[(t0 + 2) * 64 + l];
    const uint32_t v3 = v_s[(t0 + 3) * 64 + l];
    const float2 f0 = __half22float2(*(const __half2*)&v0);
    const float2 f1 = __half22float2(*(const __half2*)&v1);
    const float2 f2 = __half22float2(*(const __half2*)&v2);
    const float2 f3 = __half22float2(*(const __half2*)&v3);
    ax += pm4.x * f0.x + pm4.y * f1.x + pm4.z * f2.x + pm4.w * f3.x;
    ay += pm4.x * f0.y + pm4.y * f1.y + pm4.z * f2.y + pm4.w * f3.y;
  }

  // ---- stage results to LDS, then coalesced float4 stores ------------------
  *(float2*)&out_s[w * 128 + 2 * l] = make_float2(ax, ay);
  __syncthreads();                         // barrier 4: out_s ready
  if (u < 256) {
    const int c = u & 127;
    const int qxl = u >> 7;                // 0..1
    float4 o;
    o.x = out_s[(qxl * 4 + 0) * 128 + c];
    o.y = out_s[(qxl * 4 + 1) * 128 + c];
    o.z = out_s[(qxl * 4 + 2) * 128 + c];
    o.w = out_s[(qxl * 4 + 3) * 128 + c];
    *(float4*)&out[(size_t)c * NPOS_Q + (2 * a + qxl) * WQ + 4 * b] = o;
  }
}

// ---------------------------------------------------------------------------
extern "C" void kernel_launch(void* const* d_in, const int* in_sizes, int n_in,
                              void* d_out, int out_size, void* d_ws, size_t ws_size,
                              hipStream_t stream) {
  const float* q   = (const float*)d_in[0];
  const float* k   = (const float*)d_in[1];
  const float* v   = (const float*)d_in[2];
  const float* w_q = (const float*)d_in[3];
  const float* b_q = (const float*)d_in[4];
  const float* w_k = (const float*)d_in[5];
  const float* b_k = (const float*)d_in[6];
  float* out = (float*)d_out;

  uint4* xtqf = (uint4*)d_ws;                      // 294912 uint4 (frag q^T)
  uint4* xtkf = xtqf + 294912;                     // 73728 uint4
  uint4* wqf  = xtkf + 73728;                      // 8192 uint4
  uint4* wkf  = wqf + 8192;                        // 8192 uint4
  uint32_t* vt = (uint32_t*)(wkf + 8192);          // [2304][64] u32
  __half* qt = (__half*)(vt + (size_t)NPOS_K * 64);// [9216][256] f16
  __half* kt = qt + (size_t)NPOS_Q * C_IN;         // [2304][256] f16

  prep<<<220, 256, 0, stream>>>(q, k, v, w_q, w_k, xtqf, xtkf, vt, wqf, wkf);
  proj_mfma<<<dim3(180, 4), 256, 0, stream>>>(xtqf, xtkf, wqf, wkf,
                                              b_q, b_k, qt, kt);
  natten_attn<<<dim3(HQ / 2, WQ / 4), 512, 0, stream>>>(
      qt, kt, (const __half*)vt, out);
}